// Round 1
// baseline (574.358 us; speedup 1.0000x reference)
//
#include <hip/hip_runtime.h>
#include <hip/hip_bf16.h>
#include <math.h>
#include <stdint.h>

typedef __bf16 bf16_t;
typedef bf16_t bf16x4 __attribute__((ext_vector_type(4)));
typedef bf16_t bf16x8 __attribute__((ext_vector_type(8)));
typedef float floatx4 __attribute__((ext_vector_type(4)));

#define B_     4
#define S_     4096
#define D_     1024
#define P_     1364
#define P3_    4092      // 3*P
#define NP_    5456      // 3P + P (gate cols + cell cols)
#define NPAD_  5504      // NP_ rounded up to 128
#define KPAD_  1408      // P_ rounded up to 128 (K of out-GEMM)
#define ROWS_  16384     // B*S
#define CAP_   15.0f
#define EPS_   1e-6f
#define CHUNKS_ 32
#define CLEN_   128      // S_/CHUNKS_

// ---------------- RMSNorm: x fp32 [ROWS][D] -> xn bf16 [ROWS][D] ----------------
__global__ __launch_bounds__(256) void rmsnorm_kernel(const float* __restrict__ x,
                                                      const float* __restrict__ w,
                                                      bf16_t* __restrict__ xn) {
    int row = blockIdx.x;
    int tid = threadIdx.x;
    const float4 v = ((const float4*)(x + (size_t)row * D_))[tid];
    float ss = v.x * v.x + v.y * v.y + v.z * v.z + v.w * v.w;
    #pragma unroll
    for (int off = 32; off > 0; off >>= 1) ss += __shfl_down(ss, off);
    __shared__ float red[4];
    if ((tid & 63) == 0) red[tid >> 6] = ss;
    __syncthreads();
    float tot = red[0] + red[1] + red[2] + red[3];
    float scale = rsqrtf(tot * (1.0f / (float)D_) + EPS_);
    const float4 wv = ((const float4*)w)[tid];
    bf16x4 o;
    o[0] = (bf16_t)(v.x * scale * wv.x);
    o[1] = (bf16_t)(v.y * scale * wv.y);
    o[2] = (bf16_t)(v.z * scale * wv.z);
    o[3] = (bf16_t)(v.w * scale * wv.w);
    ((bf16x4*)(xn + (size_t)row * D_))[tid] = o;
}

// ---- pack W_gate [D][3P] + W_cell [D][P] fp32 -> Wcat^T bf16 [NPAD_][D] (pad rows zero) ----
__global__ __launch_bounds__(256) void pack_wcat(const float* __restrict__ Wg,
                                                 const float* __restrict__ Wc,
                                                 bf16_t* __restrict__ Wt) {
    __shared__ float tile[32][33];
    int kt = blockIdx.x * 32;   // k in [0,1024)
    int nt = blockIdx.y * 32;   // n in [0,NPAD_)
    int tx = threadIdx.x & 31;
    int ty = threadIdx.x >> 5;  // 0..7
    #pragma unroll
    for (int i = 0; i < 4; i++) {
        int k = kt + ty + 8 * i;
        int n = nt + tx;
        float val = 0.f;
        if (n < P3_)      val = Wg[(size_t)k * P3_ + n];
        else if (n < NP_) val = Wc[(size_t)k * P_ + (n - P3_)];
        tile[ty + 8 * i][tx] = val;
    }
    __syncthreads();
    #pragma unroll
    for (int i = 0; i < 4; i++) {
        int n = nt + ty + 8 * i;
        int k = kt + tx;
        Wt[(size_t)n * D_ + k] = (bf16_t)tile[tx][ty + 8 * i];
    }
}

// ---- pack W_out [P][D] fp32 -> Wout^T bf16 [D][KPAD_] (pad cols zero) ----
__global__ __launch_bounds__(256) void pack_wout(const float* __restrict__ Wo,
                                                 bf16_t* __restrict__ Wt) {
    __shared__ float tile[32][33];
    int pt = blockIdx.x * 32;   // p in [0,KPAD_)
    int dt = blockIdx.y * 32;   // d in [0,1024)
    int tx = threadIdx.x & 31;
    int ty = threadIdx.x >> 5;
    #pragma unroll
    for (int i = 0; i < 4; i++) {
        int p = pt + ty + 8 * i;
        int d = dt + tx;
        float val = (p < P_) ? Wo[(size_t)p * D_ + d] : 0.f;
        tile[ty + 8 * i][tx] = val;
    }
    __syncthreads();
    #pragma unroll
    for (int i = 0; i < 4; i++) {
        int d = dt + ty + 8 * i;
        int p = pt + tx;
        Wt[(size_t)d * KPAD_ + p] = (bf16_t)tile[tx][ty + 8 * i];
    }
}

__device__ __forceinline__ float softcap_sigmoid(float g) {
    float t = tanhf(g * (1.0f / CAP_));
    return 1.0f / (1.0f + __expf(-CAP_ * t));
}

// ---------------- 128x128 MFMA GEMM, A [M][K] bf16, Bt [N][K] bf16 ----------------
// EPI 0: activation epilogue -> bf16 out (gate cols softcap-sigmoid, cell cols tanh)
// EPI 1: residual add epilogue -> fp32 out
template <int KTOT, int LDA, int LDB, int EPI>
__global__ __launch_bounds__(256) void gemm_tpl(const bf16_t* __restrict__ A,
                                                const bf16_t* __restrict__ Bt,
                                                const float* __restrict__ res,
                                                void* __restrict__ outv, int ldc) {
    __shared__ bf16_t As[128 * 64];
    __shared__ bf16_t Bs[128 * 64];
    const int tid  = threadIdx.x;
    const int wid  = tid >> 6;
    const int lane = tid & 63;
    const int m0 = blockIdx.y * 128;
    const int n0 = blockIdx.x * 128;

    floatx4 acc[4][4];
    #pragma unroll
    for (int i = 0; i < 4; i++)
        #pragma unroll
        for (int j = 0; j < 4; j++) acc[i][j] = (floatx4){0.f, 0.f, 0.f, 0.f};

    const int srow = tid >> 3;        // 0..31
    const int scol = (tid & 7) * 8;   // 0..56
    const bf16_t* Ag = A  + (size_t)(m0 + srow) * LDA + scol;
    const bf16_t* Bg = Bt + (size_t)(n0 + srow) * LDB + scol;
    bf16_t* AsW = As + wid * 8 * 64;  // wave-uniform LDS base
    bf16_t* BsW = Bs + wid * 8 * 64;

    const int wrow = (wid >> 1) * 64;
    const int wcol = (wid & 1) * 64;
    const int lrow = lane & 15;
    const int lk8  = (lane >> 4) * 8;

    for (int k0 = 0; k0 < KTOT; k0 += 64) {
        #pragma unroll
        for (int j = 0; j < 4; j++)
            __builtin_amdgcn_global_load_lds((const unsigned int*)(Ag + (size_t)(j * 32) * LDA + k0),
                                             (unsigned int*)(AsW + j * 32 * 64), 16, 0, 0);
        #pragma unroll
        for (int j = 0; j < 4; j++)
            __builtin_amdgcn_global_load_lds((const unsigned int*)(Bg + (size_t)(j * 32) * LDB + k0),
                                             (unsigned int*)(BsW + j * 32 * 64), 16, 0, 0);
        __syncthreads();
        #pragma unroll
        for (int kk = 0; kk < 2; kk++) {
            bf16x8 af[4], bfr[4];
            #pragma unroll
            for (int i = 0; i < 4; i++)
                af[i] = *(const bf16x8*)&As[(wrow + i * 16 + lrow) * 64 + kk * 32 + lk8];
            #pragma unroll
            for (int i = 0; i < 4; i++)
                bfr[i] = *(const bf16x8*)&Bs[(wcol + i * 16 + lrow) * 64 + kk * 32 + lk8];
            #pragma unroll
            for (int i = 0; i < 4; i++)
                #pragma unroll
                for (int j = 0; j < 4; j++)
                    acc[i][j] = __builtin_amdgcn_mfma_f32_16x16x32_bf16(af[i], bfr[j], acc[i][j], 0, 0, 0);
        }
        __syncthreads();
    }

    const int crow0 = m0 + wrow + (lane >> 4) * 4;
    const int ccol0 = n0 + wcol + lrow;
    if constexpr (EPI == 0) {
        bf16_t* Outp = (bf16_t*)outv;
        #pragma unroll
        for (int i = 0; i < 4; i++)
            #pragma unroll
            for (int j = 0; j < 4; j++) {
                int col = ccol0 + j * 16;
                #pragma unroll
                for (int r = 0; r < 4; r++) {
                    int row = crow0 + i * 16 + r;
                    float g = acc[i][j][r];
                    float v = (col < P3_) ? softcap_sigmoid(g) : tanhf(g);
                    Outp[(size_t)row * ldc + col] = (bf16_t)v;
                }
            }
    } else {
        float* Outp = (float*)outv;
        #pragma unroll
        for (int i = 0; i < 4; i++)
            #pragma unroll
            for (int j = 0; j < 4; j++) {
                int col = ccol0 + j * 16;
                #pragma unroll
                for (int r = 0; r < 4; r++) {
                    int row = crow0 + i * 16 + r;
                    Outp[(size_t)row * ldc + col] =
                        res[(size_t)row * ldc + col] + acc[i][j][r];
                }
            }
    }
}

// ---------------- chunked linear recurrence ----------------
// act layout per row (bf16, stride NPAD_): [0,P): i | [P,2P): f | [2P,3P): o | [3P,3P+P): tanh(c)
// pass 1: per (b, p, chunk) compute F = prod f, Acc = local scan end value (h_start=0)
__global__ __launch_bounds__(256) void chunk_scan1(const bf16_t* __restrict__ act,
                                                   float* __restrict__ FA) {
    int p = blockIdx.x * 256 + threadIdx.x;
    int c = blockIdx.y;
    int b = blockIdx.z;
    if (p >= P_) return;
    const bf16_t* base = act + (size_t)(b * S_ + c * CLEN_) * NPAD_;
    float F = 1.f, Acc = 0.f;
    for (int t = 0; t < CLEN_; t++) {
        const bf16_t* r = base + (size_t)t * NPAD_;
        float iv = (float)r[p];
        float fv = (float)r[P_ + p];
        float tc = (float)r[P3_ + p];
        Acc = fv * Acc + iv * tc;
        F *= fv;
    }
    size_t idx = (((size_t)b * CHUNKS_ + c) * P_ + p) * 2;
    FA[idx]     = F;
    FA[idx + 1] = Acc;
}

// pass 2: fix chunk-start h from (F,Acc) prefix, emit outputs o*tanh(h) bf16 [ROWS][KPAD_]
__global__ __launch_bounds__(256) void chunk_scan2(const bf16_t* __restrict__ act,
                                                   const float* __restrict__ FA,
                                                   const float* __restrict__ h0,
                                                   bf16_t* __restrict__ outp) {
    int p = blockIdx.x * 256 + threadIdx.x;
    int c = blockIdx.y;
    int b = blockIdx.z;
    if (p >= KPAD_) return;
    if (p >= P_) {  // zero-fill K-pad columns for GEMM2
        bf16_t z = (bf16_t)0.f;
        for (int t = 0; t < CLEN_; t++)
            outp[(size_t)(b * S_ + c * CLEN_ + t) * KPAD_ + p] = z;
        return;
    }
    float h = h0[(size_t)b * P_ + p];
    for (int j = 0; j < c; j++) {
        size_t idx = (((size_t)b * CHUNKS_ + j) * P_ + p) * 2;
        h = FA[idx + 1] + FA[idx] * h;
    }
    const bf16_t* base = act + (size_t)(b * S_ + c * CLEN_) * NPAD_;
    bf16_t* ob = outp + (size_t)(b * S_ + c * CLEN_) * KPAD_;
    for (int t = 0; t < CLEN_; t++) {
        const bf16_t* r = base + (size_t)t * NPAD_;
        float iv = (float)r[p];
        float fv = (float)r[P_ + p];
        float ov = (float)r[2 * P_ + p];
        float tc = (float)r[P3_ + p];
        h = fv * h + iv * tc;
        ob[(size_t)t * KPAD_ + p] = (bf16_t)(ov * tanhf(h));
    }
}

__global__ void copy_hidden(const float* __restrict__ hs, float* __restrict__ dst) {
    int i = blockIdx.x * 256 + threadIdx.x;
    if (i < B_ * P_) dst[i] = hs[i];
}

extern "C" void kernel_launch(void* const* d_in, const int* in_sizes, int n_in,
                              void* d_out, int out_size, void* d_ws, size_t ws_size,
                              hipStream_t stream) {
    const float* x   = (const float*)d_in[0];
    const float* hs  = (const float*)d_in[1];
    const float* lnw = (const float*)d_in[2];
    const float* Wg  = (const float*)d_in[3];
    const float* Wc  = (const float*)d_in[4];
    const float* Wo  = (const float*)d_in[5];
    float* out = (float*)d_out;

    char* ws = (char*)d_ws;
    size_t off = 0;
    auto alloc = [&](size_t bytes) {
        void* p = ws + off;
        off += (bytes + 255) & ~(size_t)255;
        return p;
    };
    // region reused: xn [ROWS][D] (phase 1-2) then outputs [ROWS][KPAD_] (phase 3-4)
    bf16_t* xn_outp = (bf16_t*)alloc((size_t)ROWS_ * KPAD_ * 2);   // 46 MB
    bf16_t* act     = (bf16_t*)alloc((size_t)ROWS_ * NPAD_ * 2);   // 180 MB
    bf16_t* WcatT   = (bf16_t*)alloc((size_t)NPAD_ * D_ * 2);      // 11 MB
    bf16_t* WoutT   = (bf16_t*)alloc((size_t)D_ * KPAD_ * 2);      // 2.9 MB
    float*  FA      = (float*)alloc((size_t)B_ * CHUNKS_ * P_ * 2 * 4); // 1.4 MB

    bf16_t* xn   = xn_outp;
    bf16_t* outp = xn_outp;

    hipLaunchKernelGGL(rmsnorm_kernel, dim3(ROWS_), dim3(256), 0, stream, x, lnw, xn);
    hipLaunchKernelGGL(pack_wcat, dim3(32, NPAD_ / 32), dim3(256), 0, stream, Wg, Wc, WcatT);
    hipLaunchKernelGGL(pack_wout, dim3(KPAD_ / 32, D_ / 32), dim3(256), 0, stream, Wo, WoutT);

    hipLaunchKernelGGL((gemm_tpl<D_, D_, D_, 0>), dim3(NPAD_ / 128, ROWS_ / 128), dim3(256), 0, stream,
                       xn, WcatT, (const float*)nullptr, (void*)act, NPAD_);

    hipLaunchKernelGGL(chunk_scan1, dim3(6, CHUNKS_, B_), dim3(256), 0, stream, act, FA);
    hipLaunchKernelGGL(chunk_scan2, dim3(6, CHUNKS_, B_), dim3(256), 0, stream, act, FA, hs, outp);

    hipLaunchKernelGGL((gemm_tpl<KPAD_, KPAD_, KPAD_, 1>), dim3(D_ / 128, ROWS_ / 128), dim3(256), 0, stream,
                       outp, WoutT, x, d_out, D_);

    hipLaunchKernelGGL(copy_hidden, dim3((B_ * P_ + 255) / 256), dim3(256), 0, stream,
                       hs, out + (size_t)ROWS_ * D_);
}

// Round 3
// 467.028 us; speedup vs baseline: 1.2298x; 1.2298x over previous
//
#include <hip/hip_runtime.h>
#include <hip/hip_bf16.h>
#include <math.h>
#include <stdint.h>

typedef __bf16 bf16_t;
typedef bf16_t bf16x4 __attribute__((ext_vector_type(4)));
typedef bf16_t bf16x8 __attribute__((ext_vector_type(8)));
typedef float floatx4 __attribute__((ext_vector_type(4)));

#define B_     4
#define S_     4096
#define D_     1024
#define P_     1364
#define P3_    4092      // 3*P
#define NP_    5456      // 3P + P
#define NPAD_  5504      // act row stride (cols actually written)
#define NB_    5632      // B-rows padded to 22 tiles of 256 for GEMM1
#define KPAD_  1408      // P_ rounded up to 128/64 (K of out-GEMM, 22 K-tiles)
#define ROWS_  16384     // B*S
#define CAP_   15.0f
#define EPS_   1e-6f
#define CHUNKS_ 32
#define CLEN_   128      // S_/CHUNKS_

// ---------------- fast transcendentals (bf16-accuracy) ----------------
__device__ __forceinline__ float fast_tanh(float x) {
    x = fminf(fmaxf(x, -15.f), 15.f);
    float e = __expf(2.f * x);
    return __fdividef(e - 1.f, e + 1.f);
}
__device__ __forceinline__ float fast_softcap_sig(float g) {
    float t = fast_tanh(g * (1.0f / CAP_));
    return __fdividef(1.f, 1.f + __expf(-CAP_ * t));
}

template <int N>
__device__ __forceinline__ void vmcnt_wait() {
    if constexpr (N == 8)      asm volatile("s_waitcnt vmcnt(8)" ::: "memory");
    else if constexpr (N == 4) asm volatile("s_waitcnt vmcnt(4)" ::: "memory");
    else if constexpr (N == 0) asm volatile("s_waitcnt vmcnt(0)" ::: "memory");
    // N < 0: no wait
}

// ---------------- RMSNorm: x fp32 [ROWS][D] -> xn bf16 [ROWS][D] ----------------
__global__ __launch_bounds__(256) void rmsnorm_kernel(const float* __restrict__ x,
                                                      const float* __restrict__ w,
                                                      bf16_t* __restrict__ xn) {
    int row = blockIdx.x;
    int tid = threadIdx.x;
    const float4 v = ((const float4*)(x + (size_t)row * D_))[tid];
    float ss = v.x * v.x + v.y * v.y + v.z * v.z + v.w * v.w;
    #pragma unroll
    for (int off = 32; off > 0; off >>= 1) ss += __shfl_down(ss, off);
    __shared__ float red[4];
    if ((tid & 63) == 0) red[tid >> 6] = ss;
    __syncthreads();
    float tot = red[0] + red[1] + red[2] + red[3];
    float scale = rsqrtf(tot * (1.0f / (float)D_) + EPS_);
    const float4 wv = ((const float4*)w)[tid];
    bf16x4 o;
    o[0] = (bf16_t)(v.x * scale * wv.x);
    o[1] = (bf16_t)(v.y * scale * wv.y);
    o[2] = (bf16_t)(v.z * scale * wv.z);
    o[3] = (bf16_t)(v.w * scale * wv.w);
    ((bf16x4*)(xn + (size_t)row * D_))[tid] = o;
}

// ---- pack W_gate [D][3P] + W_cell [D][P] fp32 -> Wcat^T bf16 [NB_][D] (pad rows zero) ----
__global__ __launch_bounds__(256) void pack_wcat(const float* __restrict__ Wg,
                                                 const float* __restrict__ Wc,
                                                 bf16_t* __restrict__ Wt) {
    __shared__ float tile[32][33];
    int kt = blockIdx.x * 32;
    int nt = blockIdx.y * 32;
    int tx = threadIdx.x & 31;
    int ty = threadIdx.x >> 5;
    #pragma unroll
    for (int i = 0; i < 4; i++) {
        int k = kt + ty + 8 * i;
        int n = nt + tx;
        float val = 0.f;
        if (n < P3_)      val = Wg[(size_t)k * P3_ + n];
        else if (n < NP_) val = Wc[(size_t)k * P_ + (n - P3_)];
        tile[ty + 8 * i][tx] = val;
    }
    __syncthreads();
    #pragma unroll
    for (int i = 0; i < 4; i++) {
        int n = nt + ty + 8 * i;
        int k = kt + tx;
        Wt[(size_t)n * D_ + k] = (bf16_t)tile[tx][ty + 8 * i];
    }
}

// ---- pack W_out [P][D] fp32 -> Wout^T bf16 [D][KPAD_] (pad cols zero) ----
__global__ __launch_bounds__(256) void pack_wout(const float* __restrict__ Wo,
                                                 bf16_t* __restrict__ Wt) {
    __shared__ float tile[32][33];
    int pt = blockIdx.x * 32;
    int dt = blockIdx.y * 32;
    int tx = threadIdx.x & 31;
    int ty = threadIdx.x >> 5;
    #pragma unroll
    for (int i = 0; i < 4; i++) {
        int p = pt + ty + 8 * i;
        int d = dt + tx;
        float val = (p < P_) ? Wo[(size_t)p * D_ + d] : 0.f;
        tile[ty + 8 * i][tx] = val;
    }
    __syncthreads();
    #pragma unroll
    for (int i = 0; i < 4; i++) {
        int d = dt + ty + 8 * i;
        int p = pt + tx;
        Wt[(size_t)d * KPAD_ + p] = (bf16_t)tile[tx][ty + 8 * i];
    }
}

// ---------------- 256x256 8-wave 4-phase MFMA GEMM with counted vmcnt ----------------
// A [M][LDA] bf16, Bt [N][LDB] bf16 (N-major). Per K-tile (BK=64) two kk-halves.
// LDS per buffer: A[kk][256 rows][32 k] 2x16KB + B same => 64KB; 2 buffers = 128KB.
// Read swizzle: 16B slot s' = s ^ ((row>>1)&3); stage source pre-applies the same XOR.
// kk0 of tile j staged in iter j-2 (phases 2,3); kk1 of tile j staged in iter j-1 (ph 0,1).
// Checkpoints: vmcnt(8) end-of-phase-1 and end-of-phase-3 (oldest 4 of <=12 outstanding).

#define PH_SYNC                                                               \
    __builtin_amdgcn_s_barrier();                                             \
    asm volatile("s_waitcnt lgkmcnt(0)" ::: "memory");                        \
    __builtin_amdgcn_sched_barrier(0);

#define MFMA_ROW(NLO)                                                         \
    _Pragma("unroll")                                                         \
    for (int m = 0; m < 8; m++) {                                             \
      acc[m][NLO]     = __builtin_amdgcn_mfma_f32_16x16x32_bf16(af[m], b0, acc[m][NLO], 0, 0, 0);     \
      acc[m][NLO + 1] = __builtin_amdgcn_mfma_f32_16x16x32_bf16(af[m], b1, acc[m][NLO + 1], 0, 0, 0); \
    }

#define K_ITER(KT, CB, DO_NXT, DO_CUR, VMA, VMB)                              \
  {                                                                           \
    _Pragma("unroll") for (int m = 0; m < 8; m++) af[m] = ldA(CB, 0, m);      \
    b0 = ldB(CB, 0, 0); b1 = ldB(CB, 0, 1);                                   \
    if (DO_NXT) stA((KT) + 1, 1, (CB) ^ 1);                                   \
    PH_SYNC                                                                   \
    __builtin_amdgcn_s_setprio(1);                                            \
    MFMA_ROW(0)                                                               \
    __builtin_amdgcn_s_setprio(0);                                            \
    __builtin_amdgcn_s_barrier();                                             \
    b0 = ldB(CB, 0, 2); b1 = ldB(CB, 0, 3);                                   \
    if (DO_NXT) stB((KT) + 1, 1, (CB) ^ 1);                                   \
    PH_SYNC                                                                   \
    __builtin_amdgcn_s_setprio(1);                                            \
    MFMA_ROW(2)                                                               \
    __builtin_amdgcn_s_setprio(0);                                            \
    vmcnt_wait<VMA>();                                                        \
    __builtin_amdgcn_s_barrier();                                             \
    _Pragma("unroll") for (int m = 0; m < 8; m++) af[m] = ldA(CB, 1, m);      \
    b0 = ldB(CB, 1, 0); b1 = ldB(CB, 1, 1);                                   \
    if (DO_CUR) stA((KT) + 2, 0, (CB));                                       \
    PH_SYNC                                                                   \
    __builtin_amdgcn_s_setprio(1);                                            \
    MFMA_ROW(0)                                                               \
    __builtin_amdgcn_s_setprio(0);                                            \
    __builtin_amdgcn_s_barrier();                                             \
    b0 = ldB(CB, 1, 2); b1 = ldB(CB, 1, 3);                                   \
    if (DO_CUR) stB((KT) + 2, 0, (CB));                                       \
    PH_SYNC                                                                   \
    __builtin_amdgcn_s_setprio(1);                                            \
    MFMA_ROW(2)                                                               \
    __builtin_amdgcn_s_setprio(0);                                            \
    vmcnt_wait<VMB>();                                                        \
    __builtin_amdgcn_s_barrier();                                             \
  }

template <int KTOT, int LDA, int LDB, int LDC, int NX, int EPI>
__global__ __launch_bounds__(512, 2) void gemm8(const bf16_t* __restrict__ A,
                                                const bf16_t* __restrict__ Bt,
                                                const float* __restrict__ res,
                                                void* __restrict__ outv) {
    constexpr int NT = KTOT / 64;
    static_assert(NT % 2 == 0 && NT >= 4, "NT must be even, >=4");
    __shared__ __align__(16) char smem[131072];

    const int tid  = threadIdx.x;
    const int wid  = tid >> 6;
    const int lane = tid & 63;
    const int l15  = lane & 15;
    const int sl4  = lane >> 4;
    const int sp    = sl4 ^ ((lane >> 1) & 3);          // read 16B-slot swizzle
    const int chunk = (lane & 3) ^ ((lane >> 3) & 3);   // stage-source inverse swizzle
    const int wrow = (wid >> 2) * 128;
    const int wcol = (wid & 3) * 64;

    // bijective XCD swizzle (grid multiple of 8), bx-major within a by-row
    constexpr int NWG = NX * (ROWS_ / 256);
    constexpr int CPX = NWG / 8;
    int lin = blockIdx.x;
    lin = (lin & 7) * CPX + (lin >> 3);
    const int by = lin / NX, bx = lin % NX;
    const int m0 = by * 256, n0 = bx * 256;

    const int srow = wid * 16 + (lane >> 2);            // 0..127
    const bf16_t* Asrc = A  + (size_t)(m0 + srow) * LDA + chunk * 8;
    const bf16_t* Bsrc = Bt + (size_t)(n0 + srow) * LDB + chunk * 8;
    const unsigned ldsA0 = (unsigned)(wid * 1024);
    const unsigned ldsB0 = 32768u + (unsigned)(wid * 1024);

    auto stA = [&](int kt, int kk, int buf) {
        const bf16_t* s = Asrc + kt * 64 + kk * 32;
        char* d = smem + ((unsigned)buf * 65536u + (unsigned)kk * 16384u + ldsA0);
        __builtin_amdgcn_global_load_lds((const unsigned*)s, (unsigned*)d, 16, 0, 0);
        __builtin_amdgcn_global_load_lds((const unsigned*)(s + (size_t)128 * LDA),
                                         (unsigned*)(d + 8192), 16, 0, 0);
    };
    auto stB = [&](int kt, int kk, int buf) {
        const bf16_t* s = Bsrc + kt * 64 + kk * 32;
        char* d = smem + ((unsigned)buf * 65536u + (unsigned)kk * 16384u + ldsB0);
        __builtin_amdgcn_global_load_lds((const unsigned*)s, (unsigned*)d, 16, 0, 0);
        __builtin_amdgcn_global_load_lds((const unsigned*)(s + (size_t)128 * LDB),
                                         (unsigned*)(d + 8192), 16, 0, 0);
    };
    auto ldA = [&](int buf, int kk, int m) -> bf16x8 {
        return *(const bf16x8*)(smem + (buf * 65536 + kk * 16384 +
                                        (wrow + m * 16 + l15) * 64 + sp * 16));
    };
    auto ldB = [&](int buf, int kk, int n) -> bf16x8 {
        return *(const bf16x8*)(smem + (buf * 65536 + 32768 + kk * 16384 +
                                        (wcol + n * 16 + l15) * 64 + sp * 16));
    };

    floatx4 acc[8][4];
    #pragma unroll
    for (int m = 0; m < 8; m++)
        #pragma unroll
        for (int n = 0; n < 4; n++) acc[m][n] = (floatx4){0.f, 0.f, 0.f, 0.f};
    bf16x8 af[8], b0, b1;

    // prologue: tile0 kk0+kk1, tile1 kk0  (12 loads; first 4 = tile0.kk0)
    stA(0, 0, 0); stB(0, 0, 0);
    stA(0, 1, 0); stB(0, 1, 0);
    stA(1, 0, 1); stB(1, 0, 1);
    vmcnt_wait<8>();
    __builtin_amdgcn_s_barrier();

    for (int kt = 0; kt < NT - 2; kt += 2) {
        K_ITER(kt,     0, true, true, 8, 8)
        K_ITER(kt + 1, 1, true, true, 8, 8)
    }
    K_ITER(NT - 2, 0, true,  false, 8, 4)
    K_ITER(NT - 1, 1, false, false, 0, -1)

    const int crow = m0 + wrow + sl4 * 4;
    const int ccol = n0 + wcol + l15;
    if constexpr (EPI == 0) {
        bf16_t* O = (bf16_t*)outv;
        #pragma unroll
        for (int m = 0; m < 8; m++)
            #pragma unroll
            for (int n = 0; n < 4; n++) {
                const int col = ccol + n * 16;
                if (col < NPAD_) {
                    #pragma unroll
                    for (int r = 0; r < 4; r++) {
                        const int row = crow + m * 16 + r;
                        float g = acc[m][n][r];
                        float v = (col < P3_) ? fast_softcap_sig(g) : fast_tanh(g);
                        O[(size_t)row * LDC + col] = (bf16_t)v;
                    }
                }
            }
    } else {
        float* O = (float*)outv;
        #pragma unroll
        for (int m = 0; m < 8; m++)
            #pragma unroll
            for (int n = 0; n < 4; n++) {
                const int col = ccol + n * 16;
                #pragma unroll
                for (int r = 0; r < 4; r++) {
                    const int row = crow + m * 16 + r;
                    O[(size_t)row * LDC + col] = res[(size_t)row * LDC + col] + acc[m][n][r];
                }
            }
    }
}

// ---------------- chunked linear recurrence ----------------
__global__ __launch_bounds__(256) void chunk_scan1(const bf16_t* __restrict__ act,
                                                   float* __restrict__ FA) {
    int p = blockIdx.x * 256 + threadIdx.x;
    int c = blockIdx.y;
    int b = blockIdx.z;
    if (p >= P_) return;
    const bf16_t* base = act + (size_t)(b * S_ + c * CLEN_) * NPAD_;
    float F = 1.f, Acc = 0.f;
    for (int t = 0; t < CLEN_; t++) {
        const bf16_t* r = base + (size_t)t * NPAD_;
        float iv = (float)r[p];
        float fv = (float)r[P_ + p];
        float tc = (float)r[P3_ + p];
        Acc = fv * Acc + iv * tc;
        F *= fv;
    }
    size_t idx = (((size_t)b * CHUNKS_ + c) * P_ + p) * 2;
    FA[idx]     = F;
    FA[idx + 1] = Acc;
}

__global__ __launch_bounds__(256) void chunk_scan2(const bf16_t* __restrict__ act,
                                                   const float* __restrict__ FA,
                                                   const float* __restrict__ h0,
                                                   bf16_t* __restrict__ outp) {
    int p = blockIdx.x * 256 + threadIdx.x;
    int c = blockIdx.y;
    int b = blockIdx.z;
    if (p >= KPAD_) return;
    if (p >= P_) {
        bf16_t z = (bf16_t)0.f;
        for (int t = 0; t < CLEN_; t++)
            outp[(size_t)(b * S_ + c * CLEN_ + t) * KPAD_ + p] = z;
        return;
    }
    float h = h0[(size_t)b * P_ + p];
    for (int j = 0; j < c; j++) {
        size_t idx = (((size_t)b * CHUNKS_ + j) * P_ + p) * 2;
        h = FA[idx + 1] + FA[idx] * h;
    }
    const bf16_t* base = act + (size_t)(b * S_ + c * CLEN_) * NPAD_;
    bf16_t* ob = outp + (size_t)(b * S_ + c * CLEN_) * KPAD_;
    for (int t = 0; t < CLEN_; t++) {
        const bf16_t* r = base + (size_t)t * NPAD_;
        float iv = (float)r[p];
        float fv = (float)r[P_ + p];
        float ov = (float)r[2 * P_ + p];
        float tc = (float)r[P3_ + p];
        h = fv * h + iv * tc;
        ob[(size_t)t * KPAD_ + p] = (bf16_t)(ov * fast_tanh(h));
    }
}

__global__ void copy_hidden(const float* __restrict__ hs, float* __restrict__ dst) {
    int i = blockIdx.x * 256 + threadIdx.x;
    if (i < B_ * P_) dst[i] = hs[i];
}

extern "C" void kernel_launch(void* const* d_in, const int* in_sizes, int n_in,
                              void* d_out, int out_size, void* d_ws, size_t ws_size,
                              hipStream_t stream) {
    const float* x   = (const float*)d_in[0];
    const float* hs  = (const float*)d_in[1];
    const float* lnw = (const float*)d_in[2];
    const float* Wg  = (const float*)d_in[3];
    const float* Wc  = (const float*)d_in[4];
    const float* Wo  = (const float*)d_in[5];
    float* out = (float*)d_out;

    char* ws = (char*)d_ws;
    size_t off = 0;
    auto alloc = [&](size_t bytes) {
        void* p = ws + off;
        off += (bytes + 255) & ~(size_t)255;
        return p;
    };
    bf16_t* xn_outp = (bf16_t*)alloc((size_t)ROWS_ * KPAD_ * 2);   // xn then outputs
    bf16_t* act     = (bf16_t*)alloc((size_t)ROWS_ * NPAD_ * 2);
    bf16_t* WcatT   = (bf16_t*)alloc((size_t)NB_ * D_ * 2);
    bf16_t* WoutT   = (bf16_t*)alloc((size_t)D_ * KPAD_ * 2);
    float*  FA      = (float*)alloc((size_t)B_ * CHUNKS_ * P_ * 2 * 4);

    bf16_t* xn   = xn_outp;
    bf16_t* outp = xn_outp;

    hipLaunchKernelGGL(rmsnorm_kernel, dim3(ROWS_), dim3(256), 0, stream, x, lnw, xn);
    hipLaunchKernelGGL(pack_wcat, dim3(32, NB_ / 32), dim3(256), 0, stream, Wg, Wc, WcatT);
    hipLaunchKernelGGL(pack_wout, dim3(KPAD_ / 32, D_ / 32), dim3(256), 0, stream, Wo, WoutT);

    hipLaunchKernelGGL((gemm8<D_, D_, D_, NPAD_, NB_ / 256, 0>),
                       dim3((NB_ / 256) * (ROWS_ / 256)), dim3(512), 0, stream,
                       xn, WcatT, (const float*)nullptr, (void*)act);

    hipLaunchKernelGGL(chunk_scan1, dim3(6, CHUNKS_, B_), dim3(256), 0, stream, act, FA);
    hipLaunchKernelGGL(chunk_scan2, dim3(6, CHUNKS_, B_), dim3(256), 0, stream, act, FA, hs, outp);

    hipLaunchKernelGGL((gemm8<KPAD_, KPAD_, KPAD_, D_, D_ / 256, 1>),
                       dim3((D_ / 256) * (ROWS_ / 256)), dim3(512), 0, stream,
                       outp, WoutT, x, d_out);

    hipLaunchKernelGGL(copy_hidden, dim3((B_ * P_ + 255) / 256), dim3(256), 0, stream,
                       hs, out + (size_t)ROWS_ * D_);
}